// Round 5
// baseline (146.368 us; speedup 1.0000x reference)
//
#include <hip/hip_runtime.h>
#include <math.h>

#define HW 262144   // 512*512 elements per batch
#define BPB 32      // blocks per batch
#define CHUNK 8192  // elements per block per input; 32KB pred + 32KB label = 64KB LDS
#define NBLK (64 * BPB)  // 2048 blocks

// Fire-and-forget global->LDS DMA, 16B per lane per instruction (1KB/wave).
// LDS dest = wave-uniform base + lane*16 (m104/m108); gaddr is per-lane.
#define GL2LDS(g, l)                                                      \
    __builtin_amdgcn_global_load_lds(                                     \
        (const __attribute__((address_space(1))) void*)(g),               \
        (__attribute__((address_space(3))) void*)(l), 16, 0, 0)

// Monotonic unsigned mapping of float bits: preserves ordering for all
// finite floats (negatives flipped, positives offset).
__device__ __forceinline__ unsigned int fmono(float f) {
    unsigned int u = __float_as_uint(f);
    return (u & 0x80000000u) ? ~u : (u | 0x80000000u);
}

__global__ __launch_bounds__(256) void reduce_kernel(
    const float* __restrict__ pred, const float* __restrict__ label,
    unsigned long long* __restrict__ pblk, unsigned long long* __restrict__ lblk,
    float* __restrict__ sblk)
{
    __shared__ __align__(16) float lds[2 * CHUNK];   // [0,8192)=pred, [8192,16384)=label

    const int bi = blockIdx.x;
    const int b = bi >> 5;            // batch
    const int chunk = bi & (BPB - 1);
    const float* pbase = pred  + (size_t)b * HW + (size_t)chunk * CHUNK;
    const float* lbase = label + (size_t)b * HW + (size_t)chunk * CHUNK;
    const int t = threadIdx.x;
    const int wave = t >> 6, lane = t & 63;
    const unsigned int base = (unsigned int)chunk * CHUNK;

    // Each wave DMAs its 2048-float segment of pred and label: 16 x 1KB
    // fire-and-forget requests in the HW queue (no VGPR results for the
    // register allocator to collapse — R1-R4 showed it pins reg MLP to ~2).
    {
        const int seg = wave * 2048 + lane * 4;      // floats
        const float* pg = pbase + seg;
        const float* lg = lbase + seg;
        float* pl = lds + wave * 2048;
        float* ll = lds + CHUNK + wave * 2048;
#pragma unroll
        for (int j = 0; j < 8; ++j) {
            GL2LDS(pg + j * 256, pl + j * 256);
            GL2LDS(lg + j * 256, ll + j * 256);
        }
    }
    __syncthreads();   // compiler emits s_waitcnt vmcnt(0) before s_barrier

    const float4* lp4 = (const float4*)lds;
    const float4* ll4 = (const float4*)(lds + CHUNK);

    float sumsq = 0.0f;
    float pmax = -INFINITY, lmax = -INFINITY;
    unsigned int pidx = 0, lidx = 0;

#pragma unroll
    for (int i = 0; i < 8; ++i) {
        const float4 p = lp4[i * 256 + t];
        const float4 l = ll4[i * 256 + t];
        const unsigned int e = base + ((unsigned int)(i * 256 + t)) * 4u;
        float d;
        d = p.x - l.x; sumsq += d * d;
        d = p.y - l.y; sumsq += d * d;
        d = p.z - l.z; sumsq += d * d;
        d = p.w - l.w; sumsq += d * d;
        // strict > keeps the first (lowest-index) occurrence within a thread
        if (p.x > pmax) { pmax = p.x; pidx = e;      }
        if (p.y > pmax) { pmax = p.y; pidx = e + 1u; }
        if (p.z > pmax) { pmax = p.z; pidx = e + 2u; }
        if (p.w > pmax) { pmax = p.w; pidx = e + 3u; }
        if (l.x > lmax) { lmax = l.x; lidx = e;      }
        if (l.y > lmax) { lmax = l.y; lidx = e + 1u; }
        if (l.z > lmax) { lmax = l.z; lidx = e + 2u; }
        if (l.w > lmax) { lmax = l.w; lidx = e + 3u; }
    }

    // pack: high 32 = monotonic value bits, low 32 = ~index so that on value
    // tie the LOWER index wins under unsigned max (matches jnp.argmax).
    unsigned long long ppk = ((unsigned long long)fmono(pmax) << 32) | (unsigned long long)(0xFFFFFFFFu - pidx);
    unsigned long long lpk = ((unsigned long long)fmono(lmax) << 32) | (unsigned long long)(0xFFFFFFFFu - lidx);

    // wave(64) shuffle reduction
    for (int off = 32; off > 0; off >>= 1) {
        sumsq += __shfl_down(sumsq, off);
        unsigned long long o;
        o = __shfl_down(ppk, off); if (o > ppk) ppk = o;
        o = __shfl_down(lpk, off); if (o > lpk) lpk = o;
    }

    __shared__ float s_sum[4];
    __shared__ unsigned long long s_pp[4], s_lp[4];
    if (lane == 0) { s_sum[wave] = sumsq; s_pp[wave] = ppk; s_lp[wave] = lpk; }
    __syncthreads();
    if (t == 0) {
        float s = s_sum[0] + s_sum[1] + s_sum[2] + s_sum[3];
        unsigned long long Pk = s_pp[0], Lk = s_lp[0];
#pragma unroll
        for (int i = 1; i < 4; ++i) {
            if (s_pp[i] > Pk) Pk = s_pp[i];
            if (s_lp[i] > Lk) Lk = s_lp[i];
        }
        // Atomic-free: every block writes its own slot (no memset needed).
        pblk[bi] = Pk;
        lblk[bi] = Lk;
        sblk[bi] = s;
    }
}

// One block, 1024 threads: reduces 2048 per-block partials.
__global__ __launch_bounds__(1024) void finalize_kernel(
    const unsigned long long* __restrict__ pblk,
    const unsigned long long* __restrict__ lblk,
    const float* __restrict__ sblk,
    float* __restrict__ out)
{
    const int t = threadIdx.x;  // 0..1023

    // global mse: sum of all 2048 partials
    float s = sblk[t] + sblk[t + 1024];
    for (int off = 32; off > 0; off >>= 1) s += __shfl_down(s, off);
    __shared__ float ss[16];
    const int wave = t >> 6;
    if ((t & 63) == 0) ss[wave] = s;

    // per-batch argmax over 32 chunk partials: batch = t>>4, j = t&15
    const int batch = t >> 4, j = t & 15;
    unsigned long long Pv = pblk[batch * 32 + j];
    unsigned long long o  = pblk[batch * 32 + j + 16];
    if (o > Pv) Pv = o;
    unsigned long long Lv = lblk[batch * 32 + j];
    o = lblk[batch * 32 + j + 16];
    if (o > Lv) Lv = o;
    for (int off = 8; off > 0; off >>= 1) {
        o = __shfl_down(Pv, off, 16); if (o > Pv) Pv = o;
        o = __shfl_down(Lv, off, 16); if (o > Lv) Lv = o;
    }
    __shared__ float dd[64];
    if (j == 0) {
        const unsigned int ip = 0xFFFFFFFFu - (unsigned int)(Pv & 0xFFFFFFFFull);
        const unsigned int il = 0xFFFFFFFFu - (unsigned int)(Lv & 0xFFFFFFFFull);
        const float rp = (float)(ip >> 9), cp = (float)(ip & 511u);
        const float rl = (float)(il >> 9), cl = (float)(il & 511u);
        dd[batch] = (rp - rl) * (rp - rl) + (cp - cl) * (cp - cl);
    }
    __syncthreads();
    if (t < 64) {
        float d = dd[t];
        for (int off = 32; off > 0; off >>= 1) d += __shfl_down(d, off);
        if (t == 0) {
            float m = 0.0f;
#pragma unroll
            for (int i = 0; i < 16; ++i) m += ss[i];
            const float alpha = (d != 0.0f) ? (m / d) : 1.0f;
            out[0] = (m + 0.25f * alpha * d) / 64.0f;
        }
    }
}

extern "C" void kernel_launch(void* const* d_in, const int* in_sizes, int n_in,
                              void* d_out, int out_size, void* d_ws, size_t ws_size,
                              hipStream_t stream) {
    const float* pred  = (const float*)d_in[0];
    const float* label = (const float*)d_in[1];
    float* out = (float*)d_out;

    unsigned long long* pblk = (unsigned long long*)d_ws;  // 2048 packed pred argmax
    unsigned long long* lblk = pblk + NBLK;                // 2048 packed label argmax
    float* sblk = (float*)(lblk + NBLK);                   // 2048 mse partials

    reduce_kernel<<<dim3(NBLK), dim3(256), 0, stream>>>(pred, label, pblk, lblk, sblk);
    finalize_kernel<<<dim3(1), dim3(1024), 0, stream>>>(pblk, lblk, sblk, out);
}